// Round 4
// baseline (664.282 us; speedup 1.0000x reference)
//
#include <hip/hip_runtime.h>

typedef unsigned short u16;
typedef unsigned int u32;
typedef __attribute__((ext_vector_type(8))) short short8;
typedef __attribute__((ext_vector_type(4))) float f32x4;

__device__ __forceinline__ float b2f(u32 u) {
    union { u32 i; float f; } x; x.i = u << 16; return x.f;
}
__device__ __forceinline__ u16 f2b(float f) {
    union { float f; u32 i; } x; x.f = f;
    u32 u = x.i;
    u += 0x7fffu + ((u >> 16) & 1u);
    return (u16)(u >> 16);
}
__device__ __forceinline__ u32 pack2(float a, float b) {
    return (u32)f2b(a) | ((u32)f2b(b) << 16);
}
__device__ __forceinline__ void gl_lds16(const u16* g, u16* l) {
    __builtin_amdgcn_global_load_lds(
        (const __attribute__((address_space(1))) u32*)g,
        (__attribute__((address_space(3))) u32*)l, 16, 0, 0);
}
// inline-asm LDS read with compile-time offset immediate: invisible to the
// compiler's LDS-DMA hazard tracking (no per-phase vmcnt(0) drains) and no
// per-read address VALU/VGPR cost (r2/r3 lessons). Ordering vs MFMA is
// manual: lgkmcnt(0) + sched_barrier(0) (rule 18).
#define DSR_C(O) else if constexpr (OFF == O) \
    asm volatile("ds_read_b128 %0, %1 offset:" #O : "=v"(r) : "v"(b))
template <int OFF>
__device__ __forceinline__ short8 dsr(u32 b) {
    short8 r;
    if constexpr (OFF == 0) asm volatile("ds_read_b128 %0, %1" : "=v"(r) : "v"(b));
    DSR_C(2048); DSR_C(4096); DSR_C(6144);
    DSR_C(16384); DSR_C(18432); DSR_C(20480); DSR_C(22528);
    else asm volatile("ds_read_b128 %0, %1" : "=v"(r) : "v"(b + OFF));
    return r;
}

// ---------------- rope tables: cos/sin for 16384 positions x 32 pairs ----------------
__global__ void rope_tab(float* __restrict__ cosT, float* __restrict__ sinT) {
    int idx = blockIdx.x * 256 + threadIdx.x;      // < 524288
    int n = idx >> 5, i = idx & 31;
    float inv = exp2f(-(float)i * 0.41524101186091903f);  // log2(10000)/32
    float ang = (float)n * inv;
    float s, c;
    sincosf(ang, &s, &c);
    cosT[idx] = c; sinT[idx] = s;
}

// ---------------- weight convert + transpose to bf16 N-major ----------------
__global__ void conv_w(const float* __restrict__ Wq, const float* __restrict__ Wkv,
                       const float* __restrict__ Wo,
                       u16* __restrict__ wqkvT, u16* __restrict__ woT) {
    int idx = blockIdx.x * 256 + threadIdx.x;      // < 1048576
    if (idx < 786432) {                            // 1536 x 512
        int n = idx >> 9, k = idx & 511;
        float v = (n < 512) ? Wq[k * 512 + n] : Wkv[k * 1024 + (n - 512)];
        wqkvT[idx] = f2b(v);
    } else {
        int j = idx - 786432;                      // 512 x 512
        int n = j >> 9, k = j & 511;
        woT[j] = f2b(Wo[k * 512 + n]);
    }
}

// ---------------- RMSNorm: one wave per 512-col row, bf16 out ----------------
__launch_bounds__(256)
__global__ void rmsnorm_k(const float* __restrict__ x, const float* __restrict__ g,
                          u16* __restrict__ xn) {
    int row  = blockIdx.x * 4 + (threadIdx.x >> 6);
    int lane = threadIdx.x & 63;
    const float4* p = (const float4*)(x + (size_t)row * 512);
    float4 a = p[lane * 2], b = p[lane * 2 + 1];
    float ss = a.x*a.x + a.y*a.y + a.z*a.z + a.w*a.w
             + b.x*b.x + b.y*b.y + b.z*b.z + b.w*b.w;
#pragma unroll
    for (int off = 1; off < 64; off <<= 1) ss += __shfl_xor(ss, off);
    float scale = rsqrtf(ss * (1.0f / 512.0f) + 1.1920929e-07f);
    const float4* gp = (const float4*)g;
    float4 g0 = gp[lane * 2], g1 = gp[lane * 2 + 1];
    uint4 u;
    u.x = pack2(a.x * scale * g0.x, a.y * scale * g0.y);
    u.y = pack2(a.z * scale * g0.z, a.w * scale * g0.w);
    u.z = pack2(b.x * scale * g1.x, b.y * scale * g1.y);
    u.w = pack2(b.z * scale * g1.z, b.w * scale * g1.w);
    *(uint4*)(xn + (size_t)row * 512 + lane * 8) = u;
}

// ---------------- GEMM, 128x128 tile, BK=64, 4 waves, double-buffered counted-vmcnt ----
// Goal vs r3's 256^2 8-phase: 2 blocks/CU (64 KB LDS, <=256 regs) so one block's
// prologue drain + epilogue store tail overlaps the other block's compute
// (r3 post-mortem: ~13 us/round of dead time at 1 block/CU explained the gap).
// Per K-tile: vmcnt(8) -> barrier -> 16x dsr frag reads -> lgkm0 -> barrier ->
// STAGE(kt+2) -> 32 MFMA. Ledger (8 loads/STAGE): prologue S0,S1; steady state
// keeps 2 stages in flight, vmcnt(8) retires exactly the consumed one; TILE7
// drains vmcnt(0). lgkm0-before-barrier makes the buffer overwrite race-free.
// MODE 0: M=65536,N=1536 (q|k|v), 6144 blocks; reversed-batch A rows for n0>=512.
// MODE 1: M=65536,N=512, 2048 blocks, fp32 epilogue.
template <int MODE>
__launch_bounds__(256, 2)
__global__ void gemm_db(const u16* __restrict__ A, const u16* __restrict__ Bt,
                        u16* __restrict__ oq, u16* __restrict__ ok,
                        u16* __restrict__ ov, float* __restrict__ of) {
    __shared__ u16 As[2][8192];   // [buf][16 chunks * 512 u16] = 16 KB per buf
    __shared__ u16 Bs[2][8192];
    const int tid  = threadIdx.x;
    const int lane = tid & 63, w = tid >> 6;       // 4 waves
    const int w0 = w & 1, w1 = w >> 1;             // 2 x 2 wave grid
    const int l15 = lane & 15, l4 = lane >> 4;
    const int lr = lane >> 3;
    const int sg8 = ((lane & 7) ^ lr) * 8;         // XOR-swizzled source chunk (u16 elems)

    // ds_read bases (LDS byte offsets); buf/fragment selects are imm offsets.
    // Swizzled chunk ch=(ks*4+l4)^(row&7) depends only on ks and l15&7.
    const u32 asb = (u32)(uintptr_t)&As[0][0];
    const u32 bsb = (u32)(uintptr_t)&Bs[0][0];
    const int chx0 = l4 ^ (l15 & 7);
    const int chx1 = (4 + l4) ^ (l15 & 7);
    const u32 aB0 = asb + (u32)((w0 * 64 + l15) * 128 + chx0 * 16);
    const u32 aB1 = asb + (u32)((w0 * 64 + l15) * 128 + chx1 * 16);
    const u32 bB0 = bsb + (u32)((w1 * 64 + l15) * 128 + chx0 * 16);
    const u32 bB1 = bsb + (u32)((w1 * 64 + l15) * 128 + chx1 * 16);

    const int idx = blockIdx.x;
    const int xcd = idx & 7, rest = idx >> 3;
    int j, mg;
    if (MODE == 0) { j = rest % 12; mg = rest / 12; }
    else           { j = rest & 3;  mg = rest >> 2; }
    const int t0 = (mg * 8 + xcd) * 128;
    const int n0 = j * 128;
    int arow0 = t0;
    if (MODE == 0 && n0 >= 512) {
        int b = t0 >> 14;
        arow0 = (((b + 2) & 3) << 14) | (t0 & 16383);
    }

#define STAGE(buf, kt) do {                                                                  \
        _Pragma("unroll") for (int c_ = 0; c_ < 4; ++c_) {                                   \
            int ca_ = w * 4 + c_;                                                            \
            gl_lds16(A  + (size_t)(arow0 + ca_ * 8 + lr) * 512 + (kt) * 64 + sg8,            \
                     &As[buf][ca_ * 512]);                                                   \
            gl_lds16(Bt + (size_t)(n0    + ca_ * 8 + lr) * 512 + (kt) * 64 + sg8,            \
                     &Bs[buf][ca_ * 512]);                                                   \
        } } while (0)
#define LDT(rb) do {                                                                         \
        aF[0][0] = dsr<(rb) * 16384 +    0>(aB0); aF[0][1] = dsr<(rb) * 16384 +    0>(aB1);  \
        aF[1][0] = dsr<(rb) * 16384 + 2048>(aB0); aF[1][1] = dsr<(rb) * 16384 + 2048>(aB1);  \
        aF[2][0] = dsr<(rb) * 16384 + 4096>(aB0); aF[2][1] = dsr<(rb) * 16384 + 4096>(aB1);  \
        aF[3][0] = dsr<(rb) * 16384 + 6144>(aB0); aF[3][1] = dsr<(rb) * 16384 + 6144>(aB1);  \
        bF[0][0] = dsr<(rb) * 16384 +    0>(bB0); bF[0][1] = dsr<(rb) * 16384 +    0>(bB1);  \
        bF[1][0] = dsr<(rb) * 16384 + 2048>(bB0); bF[1][1] = dsr<(rb) * 16384 + 2048>(bB1);  \
        bF[2][0] = dsr<(rb) * 16384 + 4096>(bB0); bF[2][1] = dsr<(rb) * 16384 + 4096>(bB1);  \
        bF[3][0] = dsr<(rb) * 16384 + 6144>(bB0); bF[3][1] = dsr<(rb) * 16384 + 6144>(bB1);  \
    } while (0)
#define MMA() do {                                                                           \
        _Pragma("unroll") for (int mi_ = 0; mi_ < 4; ++mi_)                                  \
        _Pragma("unroll") for (int ni_ = 0; ni_ < 4; ++ni_)                                  \
        _Pragma("unroll") for (int ks_ = 0; ks_ < 2; ++ks_)                                  \
            acc[mi_][ni_] = __builtin_amdgcn_mfma_f32_16x16x32_bf16(                         \
                aF[mi_][ks_], bF[ni_][ks_], acc[mi_][ni_], 0, 0, 0);                         \
    } while (0)
#define TILE(kt, rb, WC) do {                                                                \
        asm volatile("s_waitcnt vmcnt(" #WC ")" ::: "memory");                               \
        __builtin_amdgcn_sched_barrier(0);                                                   \
        __builtin_amdgcn_s_barrier();                                                        \
        LDT(rb);                                                                             \
        asm volatile("s_waitcnt lgkmcnt(0)" ::: "memory");                                   \
        __builtin_amdgcn_sched_barrier(0);                                                   \
        __builtin_amdgcn_s_barrier();                                                        \
        if ((kt) < 6) STAGE(rb, (kt) + 2);                                                   \
        __builtin_amdgcn_sched_barrier(0);                                                   \
        __builtin_amdgcn_s_setprio(1); MMA(); __builtin_amdgcn_s_setprio(0);                 \
    } while (0)

    f32x4 acc[4][4];
#pragma unroll
    for (int mi = 0; mi < 4; ++mi)
#pragma unroll
        for (int ni = 0; ni < 4; ++ni) acc[mi][ni] = (f32x4){0.f, 0.f, 0.f, 0.f};
    short8 aF[4][2], bF[4][2];

    STAGE(0, 0); STAGE(1, 1);
    TILE(0, 0, 8); TILE(1, 1, 8); TILE(2, 0, 8); TILE(3, 1, 8);
    TILE(4, 0, 8); TILE(5, 1, 8); TILE(6, 0, 8); TILE(7, 1, 0);

    // epilogue: C row = (l4*4+r), col = l15 within each 16x16 tile
#pragma unroll
    for (int mi = 0; mi < 4; ++mi) {
#pragma unroll
        for (int ni = 0; ni < 4; ++ni) {
#pragma unroll
            for (int r = 0; r < 4; ++r) {
                int grow = t0 + w0 * 64 + mi * 16 + l4 * 4 + r;
                int gcol = n0 + w1 * 64 + ni * 16 + l15;
                float val = acc[mi][ni][r];
                if (MODE == 1) {
                    of[(size_t)grow * 512 + gcol] = val;
                } else {
                    if (n0 < 512) {
                        oq[(size_t)grow * 512 + gcol] = f2b(val);
                    } else if (n0 < 1024) {
                        ok[(size_t)grow * 512 + (gcol - 512)] = f2b(val);
                    } else {
                        int c = gcol - 1024;
                        ov[(size_t)grow * 512 + c] = f2b(val);
                        int bb = grow >> 14, nn = grow & 16383;
                        of[((size_t)(bb * 8 + (c >> 6)) << 20) + (size_t)nn * 64 + (c & 63)] = val;
                    }
                }
            }
        }
    }
#undef STAGE
#undef LDT
#undef MMA
#undef TILE
}

// ---------------- windowed attention: one block per (b, window, head) ----------------
// Q 64x64, K/V 68x64 (4 persistent-mem + 64 tokens), RoPE fused at staging.
__launch_bounds__(256)
__global__ void attn_win(const u16* __restrict__ q_buf, const u16* __restrict__ k_buf,
                         const u16* __restrict__ v_buf, const float* __restrict__ tm,
                         const float* __restrict__ cosT, const float* __restrict__ sinT,
                         u16* __restrict__ o_buf) {
    __shared__ u16 qs[64 * 72];    // [qrow][dh],  stride 72 bf16 (144 B)
    __shared__ u16 ks[80 * 72];    // [key][dh],   rows 0-3 pm, 4-67 tokens, 68-79 zero
    __shared__ u16 vt[64 * 104];   // [dh][key],   stride 104 bf16; keys 68-95 zeroed
    __shared__ u16 ps[64 * 104];   // [qrow][key]; cols 0-95 written in softmax (80-95 = 0)
    const int tid  = threadIdx.x;
    const int lane = tid & 63, w = tid >> 6;
    const int l15 = lane & 15, l4 = lane >> 4;
    const int h = blockIdx.x, wi = blockIdx.y, b = blockIdx.z;
    const int t0 = b * 16384 + wi * 64;

    // zero only what's read-but-unwritten: vt keys 68..95 (14 u32/row), ks rows 68..79
    for (int i = tid; i < 896; i += 256) {
        int d = i / 14, c = i - d * 14;
        *(u32*)&vt[d * 104 + 68 + 2 * c] = 0u;
    }
    for (int i = tid; i < 432; i += 256) ((u32*)ks)[2448 + i] = 0u;   // ks rows 68..79

    // stage task-memory (disjoint from zero regions; no barrier needed yet)
    {
        int r = tid >> 6, d = tid & 63;    // 256 threads == 4x64
        ks[r * 72 + d]   = f2b(tm[(h * 4 + r) * 64 + d]);
        vt[d * 104 + r]  = f2b(tm[2048 + (h * 4 + r) * 64 + d]);
    }
    // stage Q/K with rope
#pragma unroll
    for (int p = tid; p < 2048; p += 256) {
        int row = p >> 5, i = p & 31;
        int n = wi * 64 + row;
        float c = cosT[n * 32 + i], s = sinT[n * 32 + i];
        size_t gbase = (size_t)(t0 + row) * 512 + h * 64 + 2 * i;
        u32 qv = *(const u32*)(q_buf + gbase);
        float x0 = b2f(qv & 0xffffu), x1 = b2f(qv >> 16);
        *(u32*)&qs[row * 72 + 2 * i] = pack2(x0 * c - x1 * s, x1 * c + x0 * s);
        u32 kv = *(const u32*)(k_buf + gbase);
        x0 = b2f(kv & 0xffffu); x1 = b2f(kv >> 16);
        *(u32*)&ks[(row + 4) * 72 + 2 * i] = pack2(x0 * c - x1 * s, x1 * c + x0 * s);
    }
    // stage V transposed (u32 global loads, two u16 LDS stores)
#pragma unroll
    for (int p = tid; p < 2048; p += 256) {
        int row = p >> 5, e = p & 31;
        u32 vv = *(const u32*)(v_buf + (size_t)(t0 + row) * 512 + h * 64 + 2 * e);
        vt[(2 * e) * 104 + 4 + row]     = (u16)(vv & 0xffffu);
        vt[(2 * e + 1) * 104 + 4 + row] = (u16)(vv >> 16);
    }
    __syncthreads();

    // S = Q K^T (wave w owns q-rows [w*16, w*16+16))
    f32x4 sacc[5];
#pragma unroll
    for (int nt = 0; nt < 5; ++nt) sacc[nt] = (f32x4){0.f, 0.f, 0.f, 0.f};
#pragma unroll
    for (int ksi = 0; ksi < 2; ++ksi) {
        short8 a = *(const short8*)&qs[(w * 16 + l15) * 72 + ksi * 32 + l4 * 8];
#pragma unroll
        for (int nt = 0; nt < 5; ++nt) {
            short8 bfr = *(const short8*)&ks[(nt * 16 + l15) * 72 + ksi * 32 + l4 * 8];
            sacc[nt] = __builtin_amdgcn_mfma_f32_16x16x32_bf16(a, bfr, sacc[nt], 0, 0, 0);
        }
    }
    // softmax (rows = w*16 + l4*4 + r; cols spread over 16 lanes x 5 tiles)
    float inv_l[4];
#pragma unroll
    for (int r = 0; r < 4; ++r) {
        float sv[5];
#pragma unroll
        for (int nt = 0; nt < 5; ++nt) {
            float x = sacc[nt][r] * 0.125f;
            if (nt == 4 && l15 >= 4) x = -1e30f;   // keys >= 68 masked
            sv[nt] = x;
        }
        float m = sv[0];
#pragma unroll
        for (int nt = 1; nt < 5; ++nt) m = fmaxf(m, sv[nt]);
#pragma unroll
        for (int off = 1; off < 16; off <<= 1) m = fmaxf(m, __shfl_xor(m, off));
        float sum = 0.f;
#pragma unroll
        for (int nt = 0; nt < 5; ++nt) { sv[nt] = __expf(sv[nt] - m); sum += sv[nt]; }
#pragma unroll
        for (int off = 1; off < 16; off <<= 1) sum += __shfl_xor(sum, off);
        inv_l[r] = 1.f / sum;
        int prow = w * 16 + l4 * 4 + r;
#pragma unroll
        for (int nt = 0; nt < 5; ++nt) ps[prow * 104 + nt * 16 + l15] = f2b(sv[nt]);
        ps[prow * 104 + 80 + l15] = 0;   // pad keys 80..95 for the ksi=2 PV step
    }
    __syncthreads();

    // O = P V  (K-dim padded to 96)
    f32x4 oacc[4];
#pragma unroll
    for (int dt = 0; dt < 4; ++dt) oacc[dt] = (f32x4){0.f, 0.f, 0.f, 0.f};
#pragma unroll
    for (int ksi = 0; ksi < 3; ++ksi) {
        short8 a = *(const short8*)&ps[(w * 16 + l15) * 104 + ksi * 32 + l4 * 8];
#pragma unroll
        for (int dt = 0; dt < 4; ++dt) {
            short8 bfr = *(const short8*)&vt[(dt * 16 + l15) * 104 + ksi * 32 + l4 * 8];
            oacc[dt] = __builtin_amdgcn_mfma_f32_16x16x32_bf16(a, bfr, oacc[dt], 0, 0, 0);
        }
    }
#pragma unroll
    for (int dt = 0; dt < 4; ++dt)
#pragma unroll
        for (int r = 0; r < 4; ++r) {
            int row = w * 16 + l4 * 4 + r;
            o_buf[(size_t)(t0 + row) * 512 + h * 64 + dt * 16 + l15] =
                f2b(oacc[dt][r] * inv_l[r]);
        }
}

// ---------------- launch ----------------
extern "C" void kernel_launch(void* const* d_in, const int* in_sizes, int n_in,
                              void* d_out, int out_size, void* d_ws, size_t ws_size,
                              hipStream_t stream) {
    const float* seq    = (const float*)d_in[0];
    const float* norm_w = (const float*)d_in[5];
    const float* Wq     = (const float*)d_in[6];
    const float* Wkv    = (const float*)d_in[7];
    const float* Wo     = (const float*)d_in[8];
    const float* tmem   = (const float*)d_in[9];
    float* out   = (float*)d_out;
    float* origv = out + 33554432;          // (B=4, h=8, N=16384, d=64)

    char* ws = (char*)d_ws;
    u16* xn    = (u16*)(ws);                 // 64 MB; reused as attn_out after qkv GEMM
    u16* q_buf = (u16*)(ws + 67108864);
    u16* k_buf = (u16*)(ws + 134217728);
    u16* v_buf = (u16*)(ws + 201326592);
    u16* wqkvT = (u16*)(ws + 268435456);     // 1536x512 bf16
    u16* woT   = (u16*)(ws + 268435456 + 1572864);   // 512x512 bf16
    float* cosT = (float*)(ws + 270532608);  // 16384x32
    float* sinT = cosT + 524288;

    rope_tab<<<2048, 256, 0, stream>>>(cosT, sinT);
    conv_w<<<4096, 256, 0, stream>>>(Wq, Wkv, Wo, wqkvT, woT);
    rmsnorm_k<<<16384, 256, 0, stream>>>(seq, norm_w, xn);
    gemm_db<0><<<6144, 256, 0, stream>>>(xn, wqkvT, q_buf, k_buf, v_buf, origv);
    attn_win<<<dim3(8, 256, 4), 256, 0, stream>>>(q_buf, k_buf, v_buf, tmem, cosT, sinT, xn);
    gemm_db<1><<<2048, 256, 0, stream>>>(xn, woT, nullptr, nullptr, nullptr, out);
}